// Round 8
// baseline (3846.014 us; speedup 1.0000x reference)
//
#include <hip/hip_runtime.h>
#include <cmath>

typedef _Float16 f16x8 __attribute__((ext_vector_type(8)));
typedef float f32x4 __attribute__((ext_vector_type(4)));

__device__ __forceinline__ float sigm(float x) { return 1.0f / (1.0f + expf(-x)); }
__device__ __forceinline__ unsigned short f16b(float x) {
    _Float16 h = (_Float16)x; return __builtin_bit_cast(unsigned short, h);
}

// ---------------- weight prep: pack into per-lane MFMA B-fragment layout ----------
// frag element j of lane l = W[k0 + (l>>4)*8 + j][nt*16 + (l&15)]  (k0 = kt*32)
__global__ __launch_bounds__(256) void conv_gru(
    const float* __restrict__ gate_k, const float* __restrict__ cand_k,
    f16x8* __restrict__ gB, f16x8* __restrict__ cB, int* __restrict__ ctr)
{
    if (blockIdx.x == 0 && threadIdx.x < 8) ctr[threadIdx.x] = 0;  // chunk counters
    int i = blockIdx.x * 256 + threadIdx.x;
    if (i < 8*16*32*64) {          // gate: [e2][kt 16][nt 32][l 64]
        int l = i & 63, nt = (i >> 6) & 31, kt = (i >> 11) & 15, e2 = i >> 15;
        int k0 = kt*32 + ((l >> 4) << 3);
        int n  = (nt << 4) + (l & 15);
        const float* src = gate_k + ((size_t)(e2*512 + k0)) * 512 + n;
        f16x8 v;
        #pragma unroll
        for (int j = 0; j < 8; ++j) v[j] = (_Float16)src[(size_t)j * 512];
        gB[i] = v;
    }
    if (i < 8*16*16*64) {          // cand: [e2][kt 16][nt 16][l 64]
        int l = i & 63, nt = (i >> 6) & 15, kt = (i >> 10) & 15, e2 = i >> 14;
        int k0 = kt*32 + ((l >> 4) << 3);
        int n  = (nt << 4) + (l & 15);
        const float* src = cand_k + ((size_t)(e2*512 + k0)) * 256 + n;
        f16x8 v;
        #pragma unroll
        for (int j = 0; j < 8; ++j) v[j] = (_Float16)src[(size_t)j * 256];
        cB[i] = v;
    }
}

__global__ __launch_bounds__(256) void conv_wprod(const float* __restrict__ w1,
                                                  f16x8* __restrict__ wB)
{
    int i = blockIdx.x * 256 + threadIdx.x;   // [kt 32][nt 64][l 64]
    int l = i & 63, nt = (i >> 6) & 63, kt = i >> 12;
    int k0 = kt*32 + ((l >> 4) << 3);
    int n  = (nt << 4) + (l & 15);
    const float* src = w1 + (size_t)(2049 + k0) * 1024 + n;
    f16x8 v;
    #pragma unroll
    for (int j = 0; j < 8; ++j) v[j] = (_Float16)src[(size_t)j * 1024];
    wB[i] = v;
}

// ---------------- GRU encode: 128 blocks x 1024 thr, M=16-padded MFMA -------------
// f16 LDS segs [16 rows][256 cols], u16 idx = row*256 + (col ^ ((row&7)<<3))
__device__ __forceinline__ void gate_phase(const unsigned short* SX, const unsigned short* SH,
    unsigned short* Hdst, float* gzs, const float* st, const float* gbL,
    const f16x8* gBL, int w, int l)
{
    int arow = l & 15, sel = arow & 7, ak = l >> 4;
    const f16x8* px = (const f16x8*)SX + arow * 32;
    const f16x8* ph = (const f16x8*)SH + arow * 32;
    f32x4 acc0 = {0.f,0.f,0.f,0.f}, acc1 = {0.f,0.f,0.f,0.f};
    const f16x8* bp = gBL + l;
    int nt0 = 2*w;
    #pragma unroll
    for (int kt = 0; kt < 8; ++kt) {
        f16x8 a  = px[(kt*4 + ak) ^ sel];
        f16x8 b0 = bp[(size_t)(kt*32 + nt0) * 64];
        f16x8 b1 = bp[(size_t)(kt*32 + nt0 + 1) * 64];
        acc0 = __builtin_amdgcn_mfma_f32_16x16x32_f16(a, b0, acc0, 0, 0, 0);
        acc1 = __builtin_amdgcn_mfma_f32_16x16x32_f16(a, b1, acc1, 0, 0, 0);
    }
    #pragma unroll
    for (int kt = 0; kt < 8; ++kt) {
        f16x8 a  = ph[(kt*4 + ak) ^ sel];
        f16x8 b0 = bp[(size_t)((kt + 8)*32 + nt0) * 64];
        f16x8 b1 = bp[(size_t)((kt + 8)*32 + nt0 + 1) * 64];
        acc0 = __builtin_amdgcn_mfma_f32_16x16x32_f16(a, b0, acc0, 0, 0, 0);
        acc1 = __builtin_amdgcn_mfma_f32_16x16x32_f16(a, b1, acc1, 0, 0, 0);
    }
    if (l < 16) {   // rows 0..3 live in reg j of lanes 0..15
        #pragma unroll
        for (int h = 0; h < 2; ++h) {
            f32x4 acc = h ? acc1 : acc0;
            int col = (nt0 + h) * 16 + l;
            if (col < 256) {
                #pragma unroll
                for (int j = 0; j < 4; ++j) {
                    float rv = sigm(acc[j] + gbL[col]);
                    float rh = rv * st[j*256 + col];
                    Hdst[j*256 + (col ^ (j << 3))] = f16b(rh);
                }
            } else {
                int zc = col - 256;
                #pragma unroll
                for (int j = 0; j < 4; ++j)
                    gzs[j*256 + zc] = sigm(acc[j] + gbL[col]);
            }
        }
    }
}

template<int LAYER>
__device__ __forceinline__ void cand_phase(const unsigned short* SX, const unsigned short* SH,
    unsigned short* Xdst, unsigned short* Hstage,
    float* st, const float* oth, const float* gzs, const float* cbL, const f16x8* cBL,
    const float* __restrict__ emb, const int* tok_s, const int* len_s, int t,
    int w, int l)
{
    int arow = l & 15, sel = arow & 7, ak = l >> 4;
    const f16x8* px = (const f16x8*)SX + arow * 32;
    const f16x8* ph = (const f16x8*)SH + arow * 32;
    f32x4 acc = {0.f,0.f,0.f,0.f};
    const f16x8* bp = cBL + l;
    #pragma unroll
    for (int kt = 0; kt < 8; ++kt) {
        f16x8 a = px[(kt*4 + ak) ^ sel];
        f16x8 b = bp[(size_t)(kt*16 + w) * 64];
        acc = __builtin_amdgcn_mfma_f32_16x16x32_f16(a, b, acc, 0, 0, 0);
    }
    #pragma unroll
    for (int kt = 0; kt < 8; ++kt) {
        f16x8 a = ph[(kt*4 + ak) ^ sel];
        f16x8 b = bp[(size_t)((kt + 8)*16 + w) * 64];
        acc = __builtin_amdgcn_mfma_f32_16x16x32_f16(a, b, acc, 0, 0, 0);
    }
    if (l < 16) {
        int col = w*16 + l;
        #pragma unroll
        for (int j = 0; j < 4; ++j) {
            float cv = tanhf(acc[j] + cbL[col]);
            float z  = gzs[j*256 + col];
            float hv = st[j*256 + col];
            float hn = fmaf(z, hv - cv, cv);
            if (t < len_s[j]) st[j*256 + col] = hn;
            if (LAYER == 1) {
                Xdst[j*256 + (col ^ (j << 3))]   = f16b(hn);                 // layer-2 x (unmasked)
                Hstage[j*256 + (col ^ (j << 3))] = f16b(oth[j*256 + col]);   // stage h2
            } else {
                Xdst[j*256 + (col ^ (j << 3))]   = f16b(emb[(size_t)tok_s[j]*256 + col]); // x(t+1)
                Hstage[j*256 + (col ^ (j << 3))] = f16b(oth[j*256 + col]);   // stage h1
            }
        }
    }
}

__global__ __launch_bounds__(1024, 4) void gru_encode(
    const int* __restrict__ iq, const int* __restrict__ ir,
    const int* __restrict__ ql, const int* __restrict__ rl,
    const float* __restrict__ emb,
    const float* __restrict__ gate_b, const float* __restrict__ cand_b,
    const f16x8* __restrict__ gB, const f16x8* __restrict__ cB,
    int* __restrict__ ctr,
    float* __restrict__ Qo, float* __restrict__ Ro)
{
    int tid = threadIdx.x;
    int w = tid >> 6, l = tid & 63;

    // ---- XCD-aware self-assignment: stream the encoder whose weights live in
    // THIS XCD's L2, regardless of the blockIdx->XCD dispatch mapping.
    __shared__ int sh_ec;
    if (tid == 0) {
        unsigned xcc;
        asm volatile("s_getreg_b32 %0, hwreg(HW_REG_XCC_ID)" : "=s"(xcc));
        int e = (int)((xcc >> 1) & 3);
        int c = 0;
        #pragma unroll 1
        for (int k = 0; k < 4; ++k) {
            int ee = (e + k) & 3;
            int cand = atomicAdd(&ctr[ee], 1);
            if (cand < 32) { sh_ec = (ee << 8) | cand; break; }
        }
        (void)c;
    }
    __syncthreads();
    int enc = sh_ec >> 8;
    int chunk = sh_ec & 255;
    int b0 = chunk * 4;

    const int* toks = (enc < 2) ? iq : ir;
    const int* lens = (enc < 2) ? ql : rl;
    const bool bw = (enc & 1);

    const f16x8* gB1 = gB + (size_t)(enc*2 + 0) * 32768;
    const f16x8* gB2 = gB + (size_t)(enc*2 + 1) * 32768;
    const f16x8* cB1 = cB + (size_t)(enc*2 + 0) * 16384;
    const f16x8* cB2 = cB + (size_t)(enc*2 + 1) * 16384;

    __shared__ __align__(16) unsigned short X0[4096], X1[4096], H0[4096], H1[4096];
    __shared__ float h1s[1024], h2s[1024], gzs[1024];
    __shared__ float gbl[2][512], cbl[2][256];
    __shared__ int tok_s[4], len_s[4];

    for (int i = tid; i < 2048; i += 1024) {
        ((unsigned int*)X0)[i] = 0; ((unsigned int*)X1)[i] = 0;
        ((unsigned int*)H0)[i] = 0; ((unsigned int*)H1)[i] = 0;
    }
    h1s[tid] = 0.f; h2s[tid] = 0.f;
    if (tid < 512) {
        gbl[0][tid] = gate_b[(enc*2+0)*512 + tid];
        gbl[1][tid] = gate_b[(enc*2+1)*512 + tid];
    }
    if (tid < 256) {
        cbl[0][tid] = cand_b[(enc*2+0)*256 + tid];
        cbl[1][tid] = cand_b[(enc*2+1)*256 + tid];
    }
    if (tid < 4) len_s[tid] = lens[b0 + tid];
    __syncthreads();
    int maxlen = max(max(len_s[0], len_s[1]), max(len_s[2], len_s[3]));
    if (tid < 4) {
        int len = len_s[tid];
        tok_s[tid] = toks[(b0 + tid)*64 + (bw ? (len - 1) : 0)];
    }
    __syncthreads();
    if (tid < 512) {   // fill X0 rows 0..3 with x(0)
        int row = tid >> 7, cp = tid & 127;
        float2 xv = *(const float2*)(emb + (size_t)tok_s[row]*256 + 2*cp);
        unsigned int pk = (unsigned int)f16b(xv.x) | ((unsigned int)f16b(xv.y) << 16);
        ((unsigned int*)X0)[(row*256 + ((2*cp) ^ (row << 3))) >> 1] = pk;
    }
    __syncthreads();

    for (int t = 0; t < maxlen; ++t) {
        gate_phase(X0, H0, H1, gzs, h1s, gbl[0], gB1, w, l);
        __syncthreads();
        cand_phase<1>(X0, H1, X1, H0, h1s, h2s, gzs, cbl[0], cB1, emb, tok_s, len_s, t, w, l);
        __syncthreads();
        gate_phase(X1, H0, H1, gzs, h2s, gbl[1], gB2, w, l);
        if (tid < 4) {
            int t2 = t + 1;
            if (t2 < 64) {
                int len = len_s[tid];
                int tt = bw ? ((t2 < len) ? (len - 1 - t2) : t2) : t2;
                tok_s[tid] = toks[(b0 + tid)*64 + tt];
            }
        }
        __syncthreads();
        cand_phase<2>(X1, H1, X0, H0, h2s, h1s, gzs, cbl[1], cB2, emb, tok_s, len_s, t, w, l);
        __syncthreads();
    }

    float* outp = (enc < 2) ? Qo : Ro;
    int off = (enc & 1) ? 512 : 0;
    int r = tid >> 8, c = tid & 255;
    outp[(size_t)(b0 + r)*1024 + off + c]       = h1s[r*256 + c];
    outp[(size_t)(b0 + r)*1024 + off + 256 + c] = h2s[r*256 + c];
}

// ---------------- dist / ab (unchanged fp32) --------------------------------------
__global__ void dist_kernel(const float* __restrict__ Q, const float* __restrict__ R,
                            float* __restrict__ dist)
{
    int gidx = blockIdx.x * 256 + threadIdx.x;
    int i = gidx >> 7, j = gidx & 127;
    const float4* q4 = (const float4*)(Q + (size_t)i * 1024);
    const float4* r4 = (const float4*)(R + (size_t)j * 1024);
    float acc = 0.f;
    for (int k = 0; k < 256; ++k) {
        float4 a = q4[k], b = r4[k];
        acc += a.x * b.x + a.y * b.y + a.z * b.z + a.w * b.w;
    }
    dist[gidx] = acc;
}

__global__ __launch_bounds__(256) void ab_kernel(
    const float* __restrict__ Q, const float* __restrict__ R,
    const float* __restrict__ w1, float* __restrict__ A, float* __restrict__ Bv)
{
    int nb = blockIdx.x, rb = blockIdx.y, mat = blockIdx.z;
    int tid = threadIdx.x;
    int n = nb * 256 + tid;
    int r0 = rb * 16;
    const float* src   = mat ? R : Q;
    const float* wmain = mat ? (w1 + (size_t)3073 * 1024) : w1;
    const float* wdiff = w1 + (size_t)1025 * 1024;
    float sgn = mat ? -1.f : 1.f;

    __shared__ float Qs[16][64];
    float acc[16];
    #pragma unroll
    for (int r = 0; r < 16; ++r) acc[r] = 0.f;

    for (int k0 = 0; k0 < 1024; k0 += 64) {
        __syncthreads();
        #pragma unroll
        for (int s = 0; s < 4; ++s) {
            int e = s * 256 + tid;
            int r = e >> 6, kk = e & 63;
            Qs[r][kk] = src[(size_t)(r0 + r) * 1024 + k0 + kk];
        }
        __syncthreads();
        for (int kk = 0; kk < 64; ++kk) {
            size_t row = (size_t)(k0 + kk) * 1024 + n;
            float w = wmain[row] + sgn * wdiff[row];
            #pragma unroll
            for (int r = 0; r < 16; ++r)
                acc[r] = fmaf(Qs[r][kk], w, acc[r]);
        }
    }
    float* dst = mat ? Bv : A;
    #pragma unroll
    for (int r = 0; r < 16; ++r)
        dst[(size_t)(r0 + r) * 1024 + n] = acc[r];
}

// ---------------- pair GEMM: 128x128 tile MFMA, fused epilogue --------------------
__global__ __launch_bounds__(512, 2) void pair_gemm(
    const float* __restrict__ Q, const float* __restrict__ R,
    const float* __restrict__ Aq, const float* __restrict__ Bv,
    const float* __restrict__ dist,
    const int* __restrict__ nqi, const int* __restrict__ nri,
    const f16x8* __restrict__ wB,
    const float* __restrict__ w1, const float* __restrict__ b1,
    const float* __restrict__ w2, float* __restrict__ partial)
{
    int bm = blockIdx.x, bn = blockIdx.y;
    int tid = threadIdx.x, w = tid >> 6, l = tid & 63;
    __shared__ __align__(16) unsigned short As[4096];    // [128 rows][32 k] f16, k-octet ^ (row&3)
    __shared__ float red[2048];                          // [8 waves][128 rows][2]
    __shared__ int qis[128], ris[128];
    __shared__ float dsv[128];
    if (tid < 128) {
        int p = bm*128 + tid;
        int qi = (p < 128) ? p : nqi[p-128];
        int ri = (p < 128) ? p : nri[p-128];
        qis[tid] = qi; ris[tid] = ri; dsv[tid] = dist[qi*128 + ri];
    }
    __syncthreads();

    int srow = tid & 127, skg = tid >> 7;
    const float* qrow = Q + (size_t)qis[srow]*1024 + skg*8;
    const float* rrow = R + (size_t)ris[srow]*1024 + skg*8;

    float4 qa = *(const float4*)(qrow);
    float4 qb = *(const float4*)(qrow + 4);
    float4 ra = *(const float4*)(rrow);
    float4 rb = *(const float4*)(rrow + 4);

    f32x4 acc[8];
    #pragma unroll
    for (int m = 0; m < 8; ++m) acc[m] = (f32x4){0.f,0.f,0.f,0.f};

    for (int kt = 0; kt < 32; ++kt) {
        f16x8 prod;
        prod[0]=(_Float16)(qa.x*ra.x); prod[1]=(_Float16)(qa.y*ra.y);
        prod[2]=(_Float16)(qa.z*ra.z); prod[3]=(_Float16)(qa.w*ra.w);
        prod[4]=(_Float16)(qb.x*rb.x); prod[5]=(_Float16)(qb.y*rb.y);
        prod[6]=(_Float16)(qb.z*rb.z); prod[7]=(_Float16)(qb.w*rb.w);
        __syncthreads();
        ((f16x8*)As)[srow*4 + (skg ^ (srow & 3))] = prod;
        __syncthreads();
        if (kt + 1 < 32) {
            qa = *(const float4*)(qrow + (kt+1)*32);
            qb = *(const float4*)(qrow + (kt+1)*32 + 4);
            ra = *(const float4*)(rrow + (kt+1)*32);
            rb = *(const float4*)(rrow + (kt+1)*32 + 4);
        }
        f16x8 bf = wB[((size_t)kt*64 + bn*8 + w)*64 + l];
        #pragma unroll
        for (int mt = 0; mt < 8; ++mt) {
            f16x8 af = ((const f16x8*)As)[(mt*16 + (l & 15))*4 + ((l >> 4) ^ (l & 3))];
            acc[mt] = __builtin_amdgcn_mfma_f32_16x16x32_f16(af, bf, acc[mt], 0, 0, 0);
        }
    }

    // epilogue: per-wave 16-col partial sums -> LDS -> cross-wave reduce
    int col = bn*128 + w*16 + (l & 15);
    float wd  = w1[(size_t)1024*1024 + col];
    float b1v = b1[col];
    float w20 = w2[col*2], w21 = w2[col*2 + 1];
    #pragma unroll
    for (int mt = 0; mt < 8; ++mt) {
        float po0[4], po1[4];
        #pragma unroll
        for (int j = 0; j < 4; ++j) {
            int lr = mt*16 + (l >> 4)*4 + j;
            float h = acc[mt][j]
                    + Aq[(size_t)qis[lr]*1024 + col]
                    + Bv[(size_t)ris[lr]*1024 + col]
                    + dsv[lr]*wd + b1v;
            h = fmaxf(h, 0.f);
            po0[j] = h * w20; po1[j] = h * w21;
        }
        #pragma unroll
        for (int s = 1; s < 16; s <<= 1) {
            #pragma unroll
            for (int j = 0; j < 4; ++j) {
                po0[j] += __shfl_xor(po0[j], s, 64);
                po1[j] += __shfl_xor(po1[j], s, 64);
            }
        }
        if ((l & 15) == 0) {
            #pragma unroll
            for (int j = 0; j < 4; ++j) {
                int row = mt*16 + (l >> 4)*4 + j;
                red[(w*128 + row)*2 + 0] = po0[j];
                red[(w*128 + row)*2 + 1] = po1[j];
            }
        }
    }
    __syncthreads();
    if (tid < 256) {
        int row = tid >> 1, cc = tid & 1;
        float s = 0.f;
        #pragma unroll
        for (int ww = 0; ww < 8; ++ww) s += red[(ww*128 + row)*2 + cc];
        partial[((size_t)bn*16384 + bm*128 + row)*2 + cc] = s;
    }
}

__global__ void final_reduce(const float* __restrict__ partial,
                             const float* __restrict__ b2, float* __restrict__ out)
{
    int gidx = blockIdx.x * 256 + threadIdx.x;
    int p = gidx >> 1, c = gidx & 1;
    float s = b2[c];
    #pragma unroll
    for (int nt = 0; nt < 8; ++nt)
        s += partial[((size_t)nt * 16384 + p) * 2 + c];
    out[gidx] = s;
}

extern "C" void kernel_launch(void* const* d_in, const int* in_sizes, int n_in,
                              void* d_out, int out_size, void* d_ws, size_t ws_size,
                              hipStream_t stream) {
    const int*   iq     = (const int*)d_in[0];
    const int*   ir     = (const int*)d_in[1];
    const int*   ql     = (const int*)d_in[2];
    const int*   rl     = (const int*)d_in[3];
    const int*   nqi    = (const int*)d_in[4];
    const int*   nri    = (const int*)d_in[5];
    const float* emb    = (const float*)d_in[6];
    const float* gate_k = (const float*)d_in[7];
    const float* gate_b = (const float*)d_in[8];
    const float* cand_k = (const float*)d_in[9];
    const float* cand_b = (const float*)d_in[10];
    const float* w1     = (const float*)d_in[11];
    const float* b1     = (const float*)d_in[12];
    const float* w2     = (const float*)d_in[13];
    const float* b2     = (const float*)d_in[14];
    float* out = (float*)d_out;
    float* ws  = (float*)d_ws;

    float* Q       = ws;                  // 131072
    float* R       = ws + 131072;         // 131072
    float* A       = ws + 262144;         // 131072
    float* Bv      = ws + 393216;         // 131072
    float* dist    = ws + 524288;         // 16384
    float* partial = ws + 540672;         // 8*16384*2 = 262144
    f16x8* gB      = (f16x8*)(ws + 802816);   // 262144 frags
    f16x8* cB      = (f16x8*)(ws + 1851392);  // 131072 frags
    f16x8* wB      = (f16x8*)(ws + 2375680);  // 131072 frags
    int*   ctr     = (int*)(ws + 2899968);    // 8 ints (chunk counters)

    conv_gru<<<1024, 256, 0, stream>>>(gate_k, cand_k, gB, cB, ctr);
    conv_wprod<<<512, 256, 0, stream>>>(w1, wB);
    gru_encode<<<128, 1024, 0, stream>>>(iq, ir, ql, rl, emb, gate_b, cand_b,
                                         gB, cB, ctr, Q, R);
    dist_kernel<<<64, 256, 0, stream>>>(Q, R, dist);
    ab_kernel<<<dim3(4, 8, 2), 256, 0, stream>>>(Q, R, w1, A, Bv);
    pair_gemm<<<dim3(128, 8), 512, 0, stream>>>(Q, R, A, Bv, dist, nqi, nri,
                                                wB, w1, b1, w2, partial);
    final_reduce<<<128, 256, 0, stream>>>(partial, b2, out);
}

// Round 9
// 3658.335 us; speedup vs baseline: 1.0513x; 1.0513x over previous
//
#include <hip/hip_runtime.h>
#include <cmath>

typedef _Float16 f16x8 __attribute__((ext_vector_type(8)));
typedef float f32x4 __attribute__((ext_vector_type(4)));

#define MFMA16 __builtin_amdgcn_mfma_f32_16x16x32_f16

__device__ __forceinline__ float sigm(float x) { return 1.0f / (1.0f + expf(-x)); }
__device__ __forceinline__ unsigned short f16b(float x) {
    _Float16 h = (_Float16)x; return __builtin_bit_cast(unsigned short, h);
}

// ---------------- weight prep: pack into per-lane MFMA B-fragment layout ----------
// frag element j of lane l = W[k0 + (l>>4)*8 + j][nt*16 + (l&15)]  (k0 = kt*32)
__global__ __launch_bounds__(256) void conv_gru(
    const float* __restrict__ gate_k, const float* __restrict__ cand_k,
    f16x8* __restrict__ gB, f16x8* __restrict__ cB, int* __restrict__ ctr)
{
    if (blockIdx.x == 0 && threadIdx.x < 8) ctr[threadIdx.x] = 0;  // chunk counters
    int i = blockIdx.x * 256 + threadIdx.x;
    if (i < 8*16*32*64) {          // gate: [e2][kt 16][nt 32][l 64]
        int l = i & 63, nt = (i >> 6) & 31, kt = (i >> 11) & 15, e2 = i >> 15;
        int k0 = kt*32 + ((l >> 4) << 3);
        int n  = (nt << 4) + (l & 15);
        const float* src = gate_k + ((size_t)(e2*512 + k0)) * 512 + n;
        f16x8 v;
        #pragma unroll
        for (int j = 0; j < 8; ++j) v[j] = (_Float16)src[(size_t)j * 512];
        gB[i] = v;
    }
    if (i < 8*16*16*64) {          // cand: [e2][kt 16][nt 16][l 64]
        int l = i & 63, nt = (i >> 6) & 15, kt = (i >> 10) & 15, e2 = i >> 14;
        int k0 = kt*32 + ((l >> 4) << 3);
        int n  = (nt << 4) + (l & 15);
        const float* src = cand_k + ((size_t)(e2*512 + k0)) * 256 + n;
        f16x8 v;
        #pragma unroll
        for (int j = 0; j < 8; ++j) v[j] = (_Float16)src[(size_t)j * 256];
        cB[i] = v;
    }
}

__global__ __launch_bounds__(256) void conv_wprod(const float* __restrict__ w1,
                                                  f16x8* __restrict__ wB)
{
    int i = blockIdx.x * 256 + threadIdx.x;   // [kt 32][nt 64][l 64]
    int l = i & 63, nt = (i >> 6) & 63, kt = i >> 12;
    int k0 = kt*32 + ((l >> 4) << 3);
    int n  = (nt << 4) + (l & 15);
    const float* src = w1 + (size_t)(2049 + k0) * 1024 + n;
    f16x8 v;
    #pragma unroll
    for (int j = 0; j < 8; ++j) v[j] = (_Float16)src[(size_t)j * 1024];
    wB[i] = v;
}

// ---------------- GRU encode: 32 blocks x 1024 thr, 16 REAL rows per block --------
// f16 LDS segs [16 rows][256 cols], u16 idx = row*256 + (col ^ ((row&7)<<3))
__device__ __forceinline__ void gate_phase(const unsigned short* SX, const unsigned short* SH,
    unsigned short* Hdst, float* gzs, const float* st, const float* gbL,
    const f16x8* gBL, int w, int l)
{
    int arow = l & 15, sel = arow & 7, ak = l >> 4;
    const f16x8* px = (const f16x8*)SX + arow * 32;
    const f16x8* ph = (const f16x8*)SH + arow * 32;
    f32x4 acc0 = {0.f,0.f,0.f,0.f}, acc1 = {0.f,0.f,0.f,0.f};
    const f16x8* bp = gBL + l;
    int nt0 = 2*w;
    #pragma unroll
    for (int h = 0; h < 2; ++h) {
        const f16x8* ap = h ? ph : px;
        #pragma unroll
        for (int g = 0; g < 2; ++g) {
            int kb = h*8 + g*4, la = g*4;
            // 8 independent b-frag loads issued together (deep vmcnt pipeline)
            f16x8 b00 = bp[(size_t)((kb+0)*32 + nt0) * 64];
            f16x8 b01 = bp[(size_t)((kb+0)*32 + nt0 + 1) * 64];
            f16x8 b10 = bp[(size_t)((kb+1)*32 + nt0) * 64];
            f16x8 b11 = bp[(size_t)((kb+1)*32 + nt0 + 1) * 64];
            f16x8 b20 = bp[(size_t)((kb+2)*32 + nt0) * 64];
            f16x8 b21 = bp[(size_t)((kb+2)*32 + nt0 + 1) * 64];
            f16x8 b30 = bp[(size_t)((kb+3)*32 + nt0) * 64];
            f16x8 b31 = bp[(size_t)((kb+3)*32 + nt0 + 1) * 64];
            f16x8 a0 = ap[((la+0)*4 + ak) ^ sel];
            f16x8 a1 = ap[((la+1)*4 + ak) ^ sel];
            f16x8 a2 = ap[((la+2)*4 + ak) ^ sel];
            f16x8 a3 = ap[((la+3)*4 + ak) ^ sel];
            acc0 = MFMA16(a0, b00, acc0, 0, 0, 0); acc1 = MFMA16(a0, b01, acc1, 0, 0, 0);
            acc0 = MFMA16(a1, b10, acc0, 0, 0, 0); acc1 = MFMA16(a1, b11, acc1, 0, 0, 0);
            acc0 = MFMA16(a2, b20, acc0, 0, 0, 0); acc1 = MFMA16(a2, b21, acc1, 0, 0, 0);
            acc0 = MFMA16(a3, b30, acc0, 0, 0, 0); acc1 = MFMA16(a3, b31, acc1, 0, 0, 0);
        }
    }
    int r0 = (l >> 4) * 4;
    #pragma unroll
    for (int h = 0; h < 2; ++h) {
        f32x4 acc = h ? acc1 : acc0;
        int col = (nt0 + h) * 16 + (l & 15);
        if (col < 256) {            // r-gate (wave-uniform branch)
            #pragma unroll
            for (int j = 0; j < 4; ++j) {
                int row = r0 + j;
                float rv = sigm(acc[j] + gbL[col]);
                float rh = rv * st[row*256 + col];
                Hdst[row*256 + (col ^ ((row & 7) << 3))] = f16b(rh);
            }
        } else {                    // z-gate
            int zc = col - 256;
            #pragma unroll
            for (int j = 0; j < 4; ++j) {
                int row = r0 + j;
                gzs[row*256 + zc] = sigm(acc[j] + gbL[col]);
            }
        }
    }
}

template<int LAYER>
__device__ __forceinline__ void cand_phase(const unsigned short* SX, const unsigned short* SH,
    unsigned short* Xdst, unsigned short* Hstage,
    float* st, const float* oth, const float* gzs, const float* cbL, const f16x8* cBL,
    const float* __restrict__ emb, const int* tok_s, const int* len_s, int t,
    int w, int l)
{
    int arow = l & 15, sel = arow & 7, ak = l >> 4;
    const f16x8* px = (const f16x8*)SX + arow * 32;
    const f16x8* ph = (const f16x8*)SH + arow * 32;
    f32x4 acc = {0.f,0.f,0.f,0.f};
    const f16x8* bp = cBL + l;
    #pragma unroll
    for (int h = 0; h < 2; ++h) {
        const f16x8* ap = h ? ph : px;
        #pragma unroll
        for (int g = 0; g < 2; ++g) {
            int kb = h*8 + g*4, la = g*4;
            f16x8 b0 = bp[(size_t)((kb+0)*16 + w) * 64];
            f16x8 b1 = bp[(size_t)((kb+1)*16 + w) * 64];
            f16x8 b2 = bp[(size_t)((kb+2)*16 + w) * 64];
            f16x8 b3 = bp[(size_t)((kb+3)*16 + w) * 64];
            f16x8 a0 = ap[((la+0)*4 + ak) ^ sel];
            f16x8 a1 = ap[((la+1)*4 + ak) ^ sel];
            f16x8 a2 = ap[((la+2)*4 + ak) ^ sel];
            f16x8 a3 = ap[((la+3)*4 + ak) ^ sel];
            acc = MFMA16(a0, b0, acc, 0, 0, 0);
            acc = MFMA16(a1, b1, acc, 0, 0, 0);
            acc = MFMA16(a2, b2, acc, 0, 0, 0);
            acc = MFMA16(a3, b3, acc, 0, 0, 0);
        }
    }
    int r0 = (l >> 4) * 4;
    int col = w*16 + (l & 15);
    #pragma unroll
    for (int j = 0; j < 4; ++j) {
        int row = r0 + j;
        float cv = tanhf(acc[j] + cbL[col]);
        float z  = gzs[row*256 + col];
        float hv = st[row*256 + col];
        float hn = fmaf(z, hv - cv, cv);
        if (t < len_s[row]) st[row*256 + col] = hn;
        int sw = col ^ ((row & 7) << 3);
        if (LAYER == 1) {
            Xdst[row*256 + sw]   = f16b(hn);                         // layer-2 x (unmasked)
            Hstage[row*256 + sw] = f16b(oth[row*256 + col]);         // stage h2
        } else {
            Xdst[row*256 + sw]   = f16b(emb[(size_t)tok_s[row]*256 + col]); // x(t+1)
            Hstage[row*256 + sw] = f16b(oth[row*256 + col]);         // stage h1
        }
    }
}

__global__ __launch_bounds__(1024, 4) void gru_encode(
    const int* __restrict__ iq, const int* __restrict__ ir,
    const int* __restrict__ ql, const int* __restrict__ rl,
    const float* __restrict__ emb,
    const float* __restrict__ gate_b, const float* __restrict__ cand_b,
    const f16x8* __restrict__ gB, const f16x8* __restrict__ cB,
    int* __restrict__ ctr,
    float* __restrict__ Qo, float* __restrict__ Ro)
{
    int tid = threadIdx.x;
    int w = tid >> 6, l = tid & 63;

    // XCD-aware self-assignment (8 chunks of 16 rows per encoder)
    __shared__ int sh_ec;
    if (tid == 0) {
        unsigned xcc;
        asm volatile("s_getreg_b32 %0, hwreg(HW_REG_XCC_ID)" : "=s"(xcc));
        int e = (int)((xcc >> 1) & 3);
        #pragma unroll 1
        for (int k = 0; k < 4; ++k) {
            int ee = (e + k) & 3;
            int cand = atomicAdd(&ctr[ee], 1);
            if (cand < 8) { sh_ec = (ee << 8) | cand; break; }
        }
    }
    __syncthreads();
    int enc = sh_ec >> 8;
    int chunk = sh_ec & 255;
    int b0 = chunk * 16;

    const int* toks = (enc < 2) ? iq : ir;
    const int* lens = (enc < 2) ? ql : rl;
    const bool bw = (enc & 1);

    const f16x8* gB1 = gB + (size_t)(enc*2 + 0) * 32768;
    const f16x8* gB2 = gB + (size_t)(enc*2 + 1) * 32768;
    const f16x8* cB1 = cB + (size_t)(enc*2 + 0) * 16384;
    const f16x8* cB2 = cB + (size_t)(enc*2 + 1) * 16384;

    __shared__ __align__(16) unsigned short X0[4096], X1[4096], H0[4096], H1[4096];
    __shared__ float h1s[4096], h2s[4096], gzs[4096];
    __shared__ float gbl[2][512], cbl[2][256];
    __shared__ int tok_s[16], len_s[16];

    for (int i = tid; i < 2048; i += 1024) {
        ((unsigned int*)X0)[i] = 0; ((unsigned int*)X1)[i] = 0;
        ((unsigned int*)H0)[i] = 0; ((unsigned int*)H1)[i] = 0;
    }
    for (int i = tid; i < 4096; i += 1024) { h1s[i] = 0.f; h2s[i] = 0.f; }
    if (tid < 512) {
        gbl[0][tid] = gate_b[(enc*2+0)*512 + tid];
        gbl[1][tid] = gate_b[(enc*2+1)*512 + tid];
    }
    if (tid < 256) {
        cbl[0][tid] = cand_b[(enc*2+0)*256 + tid];
        cbl[1][tid] = cand_b[(enc*2+1)*256 + tid];
    }
    if (tid < 16) len_s[tid] = lens[b0 + tid];
    __syncthreads();
    int maxlen = 0;
    #pragma unroll
    for (int r = 0; r < 16; ++r) maxlen = max(maxlen, len_s[r]);
    if (tid < 16) {
        tok_s[tid] = toks[(b0 + tid)*64 + (bw ? (len_s[tid] - 1) : 0)];
    }
    __syncthreads();
    for (int i = tid; i < 2048; i += 1024) {   // fill X0 with x(0), 16 rows
        int row = i >> 7, cp = i & 127;
        float2 xv = *(const float2*)(emb + (size_t)tok_s[row]*256 + 2*cp);
        unsigned int pk = (unsigned int)f16b(xv.x) | ((unsigned int)f16b(xv.y) << 16);
        ((unsigned int*)X0)[(row*256 + ((2*cp) ^ ((row & 7) << 3))) >> 1] = pk;
    }
    __syncthreads();

    for (int t = 0; t < maxlen; ++t) {
        gate_phase(X0, H0, H1, gzs, h1s, gbl[0], gB1, w, l);
        __syncthreads();
        cand_phase<1>(X0, H1, X1, H0, h1s, h2s, gzs, cbl[0], cB1, emb, tok_s, len_s, t, w, l);
        __syncthreads();
        gate_phase(X1, H0, H1, gzs, h2s, gbl[1], gB2, w, l);
        if (tid < 16) {
            int t2 = t + 1;
            if (t2 < 64) {
                int len = len_s[tid];
                int tt = bw ? ((t2 < len) ? (len - 1 - t2) : t2) : t2;
                tok_s[tid] = toks[(b0 + tid)*64 + tt];
            }
        }
        __syncthreads();
        cand_phase<2>(X1, H1, X0, H0, h2s, h1s, gzs, cbl[1], cB2, emb, tok_s, len_s, t, w, l);
        __syncthreads();
    }

    float* outp = (enc < 2) ? Qo : Ro;
    int off = (enc & 1) ? 512 : 0;
    for (int i = tid; i < 4096; i += 1024) {
        int r = i >> 8, c = i & 255;
        outp[(size_t)(b0 + r)*1024 + off + c]       = h1s[r*256 + c];
        outp[(size_t)(b0 + r)*1024 + off + 256 + c] = h2s[r*256 + c];
    }
}

// ---------------- dist / ab (unchanged fp32) --------------------------------------
__global__ void dist_kernel(const float* __restrict__ Q, const float* __restrict__ R,
                            float* __restrict__ dist)
{
    int gidx = blockIdx.x * 256 + threadIdx.x;
    int i = gidx >> 7, j = gidx & 127;
    const float4* q4 = (const float4*)(Q + (size_t)i * 1024);
    const float4* r4 = (const float4*)(R + (size_t)j * 1024);
    float acc = 0.f;
    for (int k = 0; k < 256; ++k) {
        float4 a = q4[k], b = r4[k];
        acc += a.x * b.x + a.y * b.y + a.z * b.z + a.w * b.w;
    }
    dist[gidx] = acc;
}

__global__ __launch_bounds__(256) void ab_kernel(
    const float* __restrict__ Q, const float* __restrict__ R,
    const float* __restrict__ w1, float* __restrict__ A, float* __restrict__ Bv)
{
    int nb = blockIdx.x, rb = blockIdx.y, mat = blockIdx.z;
    int tid = threadIdx.x;
    int n = nb * 256 + tid;
    int r0 = rb * 16;
    const float* src   = mat ? R : Q;
    const float* wmain = mat ? (w1 + (size_t)3073 * 1024) : w1;
    const float* wdiff = w1 + (size_t)1025 * 1024;
    float sgn = mat ? -1.f : 1.f;

    __shared__ float Qs[16][64];
    float acc[16];
    #pragma unroll
    for (int r = 0; r < 16; ++r) acc[r] = 0.f;

    for (int k0 = 0; k0 < 1024; k0 += 64) {
        __syncthreads();
        #pragma unroll
        for (int s = 0; s < 4; ++s) {
            int e = s * 256 + tid;
            int r = e >> 6, kk = e & 63;
            Qs[r][kk] = src[(size_t)(r0 + r) * 1024 + k0 + kk];
        }
        __syncthreads();
        for (int kk = 0; kk < 64; ++kk) {
            size_t row = (size_t)(k0 + kk) * 1024 + n;
            float w = wmain[row] + sgn * wdiff[row];
            #pragma unroll
            for (int r = 0; r < 16; ++r)
                acc[r] = fmaf(Qs[r][kk], w, acc[r]);
        }
    }
    float* dst = mat ? Bv : A;
    #pragma unroll
    for (int r = 0; r < 16; ++r)
        dst[(size_t)(r0 + r) * 1024 + n] = acc[r];
}

// ---------------- pair GEMM: 128x128 tile MFMA, fused epilogue --------------------
__global__ __launch_bounds__(512, 2) void pair_gemm(
    const float* __restrict__ Q, const float* __restrict__ R,
    const float* __restrict__ Aq, const float* __restrict__ Bv,
    const float* __restrict__ dist,
    const int* __restrict__ nqi, const int* __restrict__ nri,
    const f16x8* __restrict__ wB,
    const float* __restrict__ w1, const float* __restrict__ b1,
    const float* __restrict__ w2, float* __restrict__ partial)
{
    int bm = blockIdx.x, bn = blockIdx.y;
    int tid = threadIdx.x, w = tid >> 6, l = tid & 63;
    __shared__ __align__(16) unsigned short As[4096];    // [128 rows][32 k] f16, k-octet ^ (row&3)
    __shared__ float red[2048];                          // [8 waves][128 rows][2]
    __shared__ int qis[128], ris[128];
    __shared__ float dsv[128];
    if (tid < 128) {
        int p = bm*128 + tid;
        int qi = (p < 128) ? p : nqi[p-128];
        int ri = (p < 128) ? p : nri[p-128];
        qis[tid] = qi; ris[tid] = ri; dsv[tid] = dist[qi*128 + ri];
    }
    __syncthreads();

    int srow = tid & 127, skg = tid >> 7;
    const float* qrow = Q + (size_t)qis[srow]*1024 + skg*8;
    const float* rrow = R + (size_t)ris[srow]*1024 + skg*8;

    float4 qa = *(const float4*)(qrow);
    float4 qb = *(const float4*)(qrow + 4);
    float4 ra = *(const float4*)(rrow);
    float4 rb = *(const float4*)(rrow + 4);

    f32x4 acc[8];
    #pragma unroll
    for (int m = 0; m < 8; ++m) acc[m] = (f32x4){0.f,0.f,0.f,0.f};

    for (int kt = 0; kt < 32; ++kt) {
        f16x8 prod;
        prod[0]=(_Float16)(qa.x*ra.x); prod[1]=(_Float16)(qa.y*ra.y);
        prod[2]=(_Float16)(qa.z*ra.z); prod[3]=(_Float16)(qa.w*ra.w);
        prod[4]=(_Float16)(qb.x*rb.x); prod[5]=(_Float16)(qb.y*rb.y);
        prod[6]=(_Float16)(qb.z*rb.z); prod[7]=(_Float16)(qb.w*rb.w);
        __syncthreads();
        ((f16x8*)As)[srow*4 + (skg ^ (srow & 3))] = prod;
        __syncthreads();
        if (kt + 1 < 32) {
            qa = *(const float4*)(qrow + (kt+1)*32);
            qb = *(const float4*)(qrow + (kt+1)*32 + 4);
            ra = *(const float4*)(rrow + (kt+1)*32);
            rb = *(const float4*)(rrow + (kt+1)*32 + 4);
        }
        f16x8 bf = wB[((size_t)kt*64 + bn*8 + w)*64 + l];
        #pragma unroll
        for (int mt = 0; mt < 8; ++mt) {
            f16x8 af = ((const f16x8*)As)[(mt*16 + (l & 15))*4 + ((l >> 4) ^ (l & 3))];
            acc[mt] = MFMA16(af, bf, acc[mt], 0, 0, 0);
        }
    }

    int col = bn*128 + w*16 + (l & 15);
    float wd  = w1[(size_t)1024*1024 + col];
    float b1v = b1[col];
    float w20 = w2[col*2], w21 = w2[col*2 + 1];
    #pragma unroll
    for (int mt = 0; mt < 8; ++mt) {
        float po0[4], po1[4];
        #pragma unroll
        for (int j = 0; j < 4; ++j) {
            int lr = mt*16 + (l >> 4)*4 + j;
            float h = acc[mt][j]
                    + Aq[(size_t)qis[lr]*1024 + col]
                    + Bv[(size_t)ris[lr]*1024 + col]
                    + dsv[lr]*wd + b1v;
            h = fmaxf(h, 0.f);
            po0[j] = h * w20; po1[j] = h * w21;
        }
        #pragma unroll
        for (int s = 1; s < 16; s <<= 1) {
            #pragma unroll
            for (int j = 0; j < 4; ++j) {
                po0[j] += __shfl_xor(po0[j], s, 64);
                po1[j] += __shfl_xor(po1[j], s, 64);
            }
        }
        if ((l & 15) == 0) {
            #pragma unroll
            for (int j = 0; j < 4; ++j) {
                int row = mt*16 + (l >> 4)*4 + j;
                red[(w*128 + row)*2 + 0] = po0[j];
                red[(w*128 + row)*2 + 1] = po1[j];
            }
        }
    }
    __syncthreads();
    if (tid < 256) {
        int row = tid >> 1, cc = tid & 1;
        float s = 0.f;
        #pragma unroll
        for (int ww = 0; ww < 8; ++ww) s += red[(ww*128 + row)*2 + cc];
        partial[((size_t)bn*16384 + bm*128 + row)*2 + cc] = s;
    }
}

__global__ void final_reduce(const float* __restrict__ partial,
                             const float* __restrict__ b2, float* __restrict__ out)
{
    int gidx = blockIdx.x * 256 + threadIdx.x;
    int p = gidx >> 1, c = gidx & 1;
    float s = b2[c];
    #pragma unroll
    for (int nt = 0; nt < 8; ++nt)
        s += partial[((size_t)nt * 16384 + p) * 2 + c];
    out[gidx] = s;
}

extern "C" void kernel_launch(void* const* d_in, const int* in_sizes, int n_in,
                              void* d_out, int out_size, void* d_ws, size_t ws_size,
                              hipStream_t stream) {
    const int*   iq     = (const int*)d_in[0];
    const int*   ir     = (const int*)d_in[1];
    const int*   ql     = (const int*)d_in[2];
    const int*   rl     = (const int*)d_in[3];
    const int*   nqi    = (const int*)d_in[4];
    const int*   nri    = (const int*)d_in[5];
    const float* emb    = (const float*)d_in[6];
    const float* gate_k = (const float*)d_in[7];
    const float* gate_b = (const float*)d_in[8];
    const float* cand_k = (const float*)d_in[9];
    const float* cand_b = (const float*)d_in[10];
    const float* w1     = (const float*)d_in[11];
    const float* b1     = (const float*)d_in[12];
    const float* w2     = (const float*)d_in[13];
    const float* b2     = (const float*)d_in[14];
    float* out = (float*)d_out;
    float* ws  = (float*)d_ws;

    float* Q       = ws;                  // 131072
    float* R       = ws + 131072;         // 131072
    float* A       = ws + 262144;         // 131072
    float* Bv      = ws + 393216;         // 131072
    float* dist    = ws + 524288;         // 16384
    float* partial = ws + 540672;         // 8*16384*2 = 262144
    f16x8* gB      = (f16x8*)(ws + 802816);   // 262144 frags
    f16x8* cB      = (f16x8*)(ws + 1851392);  // 131072 frags
    f16x8* wB      = (f16x8*)(ws + 2375680);  // 131072 frags
    int*   ctr     = (int*)(ws + 2899968);    // 8 ints (chunk counters)

    conv_gru<<<1024, 256, 0, stream>>>(gate_k, cand_k, gB, cB, ctr);
    conv_wprod<<<512, 256, 0, stream>>>(w1, wB);
    gru_encode<<<32, 1024, 0, stream>>>(iq, ir, ql, rl, emb, gate_b, cand_b,
                                        gB, cB, ctr, Q, R);
    dist_kernel<<<64, 256, 0, stream>>>(Q, R, dist);
    ab_kernel<<<dim3(4, 8, 2), 256, 0, stream>>>(Q, R, w1, A, Bv);
    pair_gemm<<<dim3(128, 8), 512, 0, stream>>>(Q, R, A, Bv, dist, nqi, nri,
                                                wB, w1, b1, w2, partial);
    final_reduce<<<128, 256, 0, stream>>>(partial, b2, out);
}

// Round 10
// 3626.950 us; speedup vs baseline: 1.0604x; 1.0087x over previous
//
#include <hip/hip_runtime.h>
#include <cmath>

typedef _Float16 f16x8 __attribute__((ext_vector_type(8)));
typedef float f32x4 __attribute__((ext_vector_type(4)));

#define MFMA16 __builtin_amdgcn_mfma_f32_16x16x32_f16
#define HS 264   // padded f32 row stride (264 % 32 = 8 -> 4 row-groups hit disjoint banks)

__device__ __forceinline__ float sigm(float x) { return 1.0f / (1.0f + expf(-x)); }
__device__ __forceinline__ unsigned short f16b(float x) {
    _Float16 h = (_Float16)x; return __builtin_bit_cast(unsigned short, h);
}
// async global->LDS, 16B per lane; LDS dest = uniform base + lane*16
__device__ __forceinline__ void glds16(const void* g, void* s) {
    __builtin_amdgcn_global_load_lds((const __attribute__((address_space(1))) void*)g,
                                     (__attribute__((address_space(3))) void*)s, 16, 0, 0);
}

// ---------------- weight prep: pack into per-lane MFMA B-fragment layout ----------
// frag element j of lane l = W[k0 + (l>>4)*8 + j][nt*16 + (l&15)]  (k0 = kt*32)
// NT loads/stores: don't leave dirty/polluting lines in the producer XCD's L2.
__global__ __launch_bounds__(256) void conv_gru(
    const float* __restrict__ gate_k, const float* __restrict__ cand_k,
    f16x8* __restrict__ gB, f16x8* __restrict__ cB, int* __restrict__ ctr)
{
    if (blockIdx.x == 0 && threadIdx.x < 8) ctr[threadIdx.x] = 0;  // encoder-claim counters
    int i = blockIdx.x * 256 + threadIdx.x;
    if (i < 8*16*32*64) {          // gate: [e2][kt 16][nt 32][l 64]
        int l = i & 63, nt = (i >> 6) & 31, kt = (i >> 11) & 15, e2 = i >> 15;
        int k0 = kt*32 + ((l >> 4) << 3);
        int n  = (nt << 4) + (l & 15);
        const float* src = gate_k + ((size_t)(e2*512 + k0)) * 512 + n;
        f16x8 v;
        #pragma unroll
        for (int j = 0; j < 8; ++j) v[j] = (_Float16)__builtin_nontemporal_load(&src[(size_t)j * 512]);
        __builtin_nontemporal_store(v, &gB[i]);
    }
    if (i < 8*16*16*64) {          // cand: [e2][kt 16][nt 16][l 64]
        int l = i & 63, nt = (i >> 6) & 15, kt = (i >> 10) & 15, e2 = i >> 14;
        int k0 = kt*32 + ((l >> 4) << 3);
        int n  = (nt << 4) + (l & 15);
        const float* src = cand_k + ((size_t)(e2*512 + k0)) * 256 + n;
        f16x8 v;
        #pragma unroll
        for (int j = 0; j < 8; ++j) v[j] = (_Float16)__builtin_nontemporal_load(&src[(size_t)j * 256]);
        __builtin_nontemporal_store(v, &cB[i]);
    }
}

__global__ __launch_bounds__(256) void conv_wprod(const float* __restrict__ w1,
                                                  f16x8* __restrict__ wB)
{
    int i = blockIdx.x * 256 + threadIdx.x;   // [kt 32][nt 64][l 64]
    int l = i & 63, nt = (i >> 6) & 63, kt = i >> 12;
    int k0 = kt*32 + ((l >> 4) << 3);
    int n  = (nt << 4) + (l & 15);
    const float* src = w1 + (size_t)(2049 + k0) * 1024 + n;
    f16x8 v;
    #pragma unroll
    for (int j = 0; j < 8; ++j) v[j] = (_Float16)__builtin_nontemporal_load(&src[(size_t)j * 1024]);
    __builtin_nontemporal_store(v, &wB[i]);
}

// ---------------- GRU encode: 256 blocks (1/CU guaranteed by 152KB LDS) -----------
// 32 blocks win a (encoder, 16-row chunk) claim on their own XCD; rest exit.
// B-frags stream via async global_load_lds, wave-private 2-deep ping-pong.
__device__ __forceinline__ void gate_phase(const unsigned short* SX, const unsigned short* SH,
    unsigned short* Hdst, float* gzs, const float* st, const float* gbL,
    const f16x8* gBL, f16x8 (*stgw)[2][64], int w, int l)
{
    int arow = l & 15, sel = arow & 7, ak = l >> 4;
    const f16x8* px = (const f16x8*)SX + arow * 32;
    const f16x8* ph = (const f16x8*)SH + arow * 32;
    const f16x8* bp = gBL + l;
    int nt0 = 2*w;
    glds16(bp + (size_t)nt0*64,       &stgw[0][0][0]);
    glds16(bp + (size_t)(nt0 + 1)*64, &stgw[0][1][0]);
    f32x4 acc0 = {0.f,0.f,0.f,0.f}, acc1 = {0.f,0.f,0.f,0.f};
    #pragma unroll
    for (int kt = 0; kt < 16; ++kt) {
        int b = kt & 1;
        if (kt < 15) {
            glds16(bp + (size_t)((kt+1)*32 + nt0)*64,     &stgw[b^1][0][0]);
            glds16(bp + (size_t)((kt+1)*32 + nt0 + 1)*64, &stgw[b^1][1][0]);
            asm volatile("s_waitcnt vmcnt(2)" ::: "memory");   // kt's pair landed
        } else {
            asm volatile("s_waitcnt vmcnt(0)" ::: "memory");
        }
        const f16x8* ap = (kt < 8) ? px : ph;
        f16x8 a  = ap[((kt & 7)*4 + ak) ^ sel];
        f16x8 b0 = stgw[b][0][l];
        f16x8 b1 = stgw[b][1][l];
        acc0 = MFMA16(a, b0, acc0, 0, 0, 0);
        acc1 = MFMA16(a, b1, acc1, 0, 0, 0);
    }
    int r0 = (l >> 4) * 4;
    #pragma unroll
    for (int h = 0; h < 2; ++h) {
        f32x4 acc = h ? acc1 : acc0;
        int col = (nt0 + h) * 16 + (l & 15);
        if (col < 256) {            // r-gate (wave-uniform branch)
            #pragma unroll
            for (int j = 0; j < 4; ++j) {
                int row = r0 + j;
                float rv = sigm(acc[j] + gbL[col]);
                float rh = rv * st[row*HS + col];
                Hdst[row*256 + (col ^ ((row & 7) << 3))] = f16b(rh);
            }
        } else {                    // z-gate
            int zc = col - 256;
            #pragma unroll
            for (int j = 0; j < 4; ++j) {
                int row = r0 + j;
                gzs[row*HS + zc] = sigm(acc[j] + gbL[col]);
            }
        }
    }
}

template<int LAYER>
__device__ __forceinline__ void cand_phase(const unsigned short* SX, const unsigned short* SH,
    unsigned short* Xdst, unsigned short* Hstage,
    float* st, const float* oth, const float* gzs, const float* cbL, const f16x8* cBL,
    f16x8 (*stgw)[2][64],
    const float* __restrict__ emb, const int* tok_s, const int* len_s, int t,
    int w, int l)
{
    int arow = l & 15, sel = arow & 7, ak = l >> 4;
    const f16x8* px = (const f16x8*)SX + arow * 32;
    const f16x8* ph = (const f16x8*)SH + arow * 32;
    const f16x8* bp = cBL + l;
    glds16(bp + (size_t)w*64, &stgw[0][0][0]);
    f32x4 acc = {0.f,0.f,0.f,0.f};
    #pragma unroll
    for (int kt = 0; kt < 16; ++kt) {
        int b = kt & 1;
        if (kt < 15) {
            glds16(bp + (size_t)((kt+1)*16 + w)*64, &stgw[b^1][0][0]);
            asm volatile("s_waitcnt vmcnt(1)" ::: "memory");
        } else {
            asm volatile("s_waitcnt vmcnt(0)" ::: "memory");
        }
        const f16x8* ap = (kt < 8) ? px : ph;
        f16x8 a  = ap[((kt & 7)*4 + ak) ^ sel];
        f16x8 bf = stgw[b][0][l];
        acc = MFMA16(a, bf, acc, 0, 0, 0);
    }
    int r0 = (l >> 4) * 4;
    int col = w*16 + (l & 15);
    #pragma unroll
    for (int j = 0; j < 4; ++j) {
        int row = r0 + j;
        float cv = tanhf(acc[j] + cbL[col]);
        float z  = gzs[row*HS + col];
        float hv = st[row*HS + col];
        float hn = fmaf(z, hv - cv, cv);
        if (t < len_s[row]) st[row*HS + col] = hn;
        int sw = col ^ ((row & 7) << 3);
        if (LAYER == 1) {
            Xdst[row*256 + sw]   = f16b(hn);                         // layer-2 x (unmasked)
            Hstage[row*256 + sw] = f16b(oth[row*HS + col]);          // stage h2
        } else {
            Xdst[row*256 + sw]   = f16b(emb[(size_t)tok_s[row]*256 + col]); // x(t+1)
            Hstage[row*256 + sw] = f16b(oth[row*HS + col]);          // stage h1
        }
    }
}

__global__ __launch_bounds__(1024, 4) void gru_encode(
    const int* __restrict__ iq, const int* __restrict__ ir,
    const int* __restrict__ ql, const int* __restrict__ rl,
    const float* __restrict__ emb,
    const float* __restrict__ gate_b, const float* __restrict__ cand_b,
    const f16x8* __restrict__ gB, const f16x8* __restrict__ cB,
    int* __restrict__ ctr,
    float* __restrict__ Qo, float* __restrict__ Ro)
{
    int tid = threadIdx.x;
    int w = tid >> 6, l = tid & 63;

    // Claim a chunk of MY XCD's encoder first (locality); fall through for
    // correctness under any dispatch topology. 256 blocks, 32 winners.
    __shared__ int sh_ec;
    if (tid == 0) {
        unsigned xcc;
        asm volatile("s_getreg_b32 %0, hwreg(HW_REG_XCC_ID)" : "=s"(xcc));
        int e = (int)((xcc >> 1) & 3);
        int ec = -1;
        #pragma unroll 1
        for (int k = 0; k < 4; ++k) {
            int ee = (e + k) & 3;
            int cand = atomicAdd(&ctr[ee], 1);
            if (cand < 8) { ec = (ee << 8) | cand; break; }
        }
        sh_ec = ec;
    }
    __syncthreads();
    if (sh_ec < 0) return;      // no work for this block
    int enc = sh_ec >> 8;
    int chunk = sh_ec & 255;
    int b0 = chunk * 16;

    const int* toks = (enc < 2) ? iq : ir;
    const int* lens = (enc < 2) ? ql : rl;
    const bool bw = (enc & 1);

    const f16x8* gB1 = gB + (size_t)(enc*2 + 0) * 32768;
    const f16x8* gB2 = gB + (size_t)(enc*2 + 1) * 32768;
    const f16x8* cB1 = cB + (size_t)(enc*2 + 0) * 16384;
    const f16x8* cB2 = cB + (size_t)(enc*2 + 1) * 16384;

    __shared__ __align__(16) f16x8 stg[16][2][2][64];    // 64KB wave-private staging
    __shared__ __align__(16) unsigned short X0[4096], X1[4096], H0[4096], H1[4096];
    __shared__ float h1s[16*HS], h2s[16*HS], gzs[16*HS];
    __shared__ float gbl[2][512], cbl[2][256];
    __shared__ int tok_s[16], len_s[16];

    for (int i = tid; i < 2048; i += 1024) {
        ((unsigned int*)X0)[i] = 0; ((unsigned int*)X1)[i] = 0;
        ((unsigned int*)H0)[i] = 0; ((unsigned int*)H1)[i] = 0;
    }
    for (int i = tid; i < 16*HS; i += 1024) { h1s[i] = 0.f; h2s[i] = 0.f; }
    if (tid < 512) {
        gbl[0][tid] = gate_b[(enc*2+0)*512 + tid];
        gbl[1][tid] = gate_b[(enc*2+1)*512 + tid];
    }
    if (tid < 256) {
        cbl[0][tid] = cand_b[(enc*2+0)*256 + tid];
        cbl[1][tid] = cand_b[(enc*2+1)*256 + tid];
    }
    if (tid < 16) len_s[tid] = lens[b0 + tid];
    __syncthreads();
    int maxlen = 0;
    #pragma unroll
    for (int r = 0; r < 16; ++r) maxlen = max(maxlen, len_s[r]);
    if (tid < 16) {
        tok_s[tid] = toks[(b0 + tid)*64 + (bw ? (len_s[tid] - 1) : 0)];
    }
    __syncthreads();
    for (int i = tid; i < 2048; i += 1024) {   // fill X0 with x(0), 16 rows
        int row = i >> 7, cp = i & 127;
        float2 xv = *(const float2*)(emb + (size_t)tok_s[row]*256 + 2*cp);
        unsigned int pk = (unsigned int)f16b(xv.x) | ((unsigned int)f16b(xv.y) << 16);
        ((unsigned int*)X0)[(row*256 + ((2*cp) ^ ((row & 7) << 3))) >> 1] = pk;
    }
    __syncthreads();

    for (int t = 0; t < maxlen; ++t) {
        gate_phase(X0, H0, H1, gzs, h1s, gbl[0], gB1, stg[w], w, l);
        __syncthreads();
        cand_phase<1>(X0, H1, X1, H0, h1s, h2s, gzs, cbl[0], cB1, stg[w], emb, tok_s, len_s, t, w, l);
        __syncthreads();
        gate_phase(X1, H0, H1, gzs, h2s, gbl[1], gB2, stg[w], w, l);
        if (tid < 16) {
            int t2 = t + 1;
            if (t2 < 64) {
                int len = len_s[tid];
                int tt = bw ? ((t2 < len) ? (len - 1 - t2) : t2) : t2;
                tok_s[tid] = toks[(b0 + tid)*64 + tt];
            }
        }
        __syncthreads();
        cand_phase<2>(X1, H1, X0, H0, h2s, h1s, gzs, cbl[1], cB2, stg[w], emb, tok_s, len_s, t, w, l);
        __syncthreads();
    }

    float* outp = (enc < 2) ? Qo : Ro;
    int off = (enc & 1) ? 512 : 0;
    for (int i = tid; i < 4096; i += 1024) {
        int r = i >> 8, c = i & 255;
        outp[(size_t)(b0 + r)*1024 + off + c]       = h1s[r*HS + c];
        outp[(size_t)(b0 + r)*1024 + off + 256 + c] = h2s[r*HS + c];
    }
}

// ---------------- dist / ab (unchanged fp32) --------------------------------------
__global__ void dist_kernel(const float* __restrict__ Q, const float* __restrict__ R,
                            float* __restrict__ dist)
{
    int gidx = blockIdx.x * 256 + threadIdx.x;
    int i = gidx >> 7, j = gidx & 127;
    const float4* q4 = (const float4*)(Q + (size_t)i * 1024);
    const float4* r4 = (const float4*)(R + (size_t)j * 1024);
    float acc = 0.f;
    for (int k = 0; k < 256; ++k) {
        float4 a = q4[k], b = r4[k];
        acc += a.x * b.x + a.y * b.y + a.z * b.z + a.w * b.w;
    }
    dist[gidx] = acc;
}

__global__ __launch_bounds__(256) void ab_kernel(
    const float* __restrict__ Q, const float* __restrict__ R,
    const float* __restrict__ w1, float* __restrict__ A, float* __restrict__ Bv)
{
    int nb = blockIdx.x, rb = blockIdx.y, mat = blockIdx.z;
    int tid = threadIdx.x;
    int n = nb * 256 + tid;
    int r0 = rb * 16;
    const float* src   = mat ? R : Q;
    const float* wmain = mat ? (w1 + (size_t)3073 * 1024) : w1;
    const float* wdiff = w1 + (size_t)1025 * 1024;
    float sgn = mat ? -1.f : 1.f;

    __shared__ float Qs[16][64];
    float acc[16];
    #pragma unroll
    for (int r = 0; r < 16; ++r) acc[r] = 0.f;

    for (int k0 = 0; k0 < 1024; k0 += 64) {
        __syncthreads();
        #pragma unroll
        for (int s = 0; s < 4; ++s) {
            int e = s * 256 + tid;
            int r = e >> 6, kk = e & 63;
            Qs[r][kk] = src[(size_t)(r0 + r) * 1024 + k0 + kk];
        }
        __syncthreads();
        for (int kk = 0; kk < 64; ++kk) {
            size_t row = (size_t)(k0 + kk) * 1024 + n;
            float w = wmain[row] + sgn * wdiff[row];
            #pragma unroll
            for (int r = 0; r < 16; ++r)
                acc[r] = fmaf(Qs[r][kk], w, acc[r]);
        }
    }
    float* dst = mat ? Bv : A;
    #pragma unroll
    for (int r = 0; r < 16; ++r)
        dst[(size_t)(r0 + r) * 1024 + n] = acc[r];
}

// ---------------- pair GEMM: 128x128 tile MFMA, fused epilogue --------------------
__global__ __launch_bounds__(512, 2) void pair_gemm(
    const float* __restrict__ Q, const float* __restrict__ R,
    const float* __restrict__ Aq, const float* __restrict__ Bv,
    const float* __restrict__ dist,
    const int* __restrict__ nqi, const int* __restrict__ nri,
    const f16x8* __restrict__ wB,
    const float* __restrict__ w1, const float* __restrict__ b1,
    const float* __restrict__ w2, float* __restrict__ partial)
{
    int bm = blockIdx.x, bn = blockIdx.y;
    int tid = threadIdx.x, w = tid >> 6, l = tid & 63;
    __shared__ __align__(16) unsigned short As[4096];    // [128 rows][32 k] f16, k-octet ^ (row&3)
    __shared__ float red[2048];                          // [8 waves][128 rows][2]
    __shared__ int qis[128], ris[128];
    __shared__ float dsv[128];
    if (tid < 128) {
        int p = bm*128 + tid;
        int qi = (p < 128) ? p : nqi[p-128];
        int ri = (p < 128) ? p : nri[p-128];
        qis[tid] = qi; ris[tid] = ri; dsv[tid] = dist[qi*128 + ri];
    }
    __syncthreads();

    int srow = tid & 127, skg = tid >> 7;
    const float* qrow = Q + (size_t)qis[srow]*1024 + skg*8;
    const float* rrow = R + (size_t)ris[srow]*1024 + skg*8;

    float4 qa = *(const float4*)(qrow);
    float4 qb = *(const float4*)(qrow + 4);
    float4 ra = *(const float4*)(rrow);
    float4 rb = *(const float4*)(rrow + 4);

    f32x4 acc[8];
    #pragma unroll
    for (int m = 0; m < 8; ++m) acc[m] = (f32x4){0.f,0.f,0.f,0.f};

    for (int kt = 0; kt < 32; ++kt) {
        f16x8 prod;
        prod[0]=(_Float16)(qa.x*ra.x); prod[1]=(_Float16)(qa.y*ra.y);
        prod[2]=(_Float16)(qa.z*ra.z); prod[3]=(_Float16)(qa.w*ra.w);
        prod[4]=(_Float16)(qb.x*rb.x); prod[5]=(_Float16)(qb.y*rb.y);
        prod[6]=(_Float16)(qb.z*rb.z); prod[7]=(_Float16)(qb.w*rb.w);
        __syncthreads();
        ((f16x8*)As)[srow*4 + (skg ^ (srow & 3))] = prod;
        __syncthreads();
        if (kt + 1 < 32) {
            qa = *(const float4*)(qrow + (kt+1)*32);
            qb = *(const float4*)(qrow + (kt+1)*32 + 4);
            ra = *(const float4*)(rrow + (kt+1)*32);
            rb = *(const float4*)(rrow + (kt+1)*32 + 4);
        }
        f16x8 bf = wB[((size_t)kt*64 + bn*8 + w)*64 + l];
        #pragma unroll
        for (int mt = 0; mt < 8; ++mt) {
            f16x8 af = ((const f16x8*)As)[(mt*16 + (l & 15))*4 + ((l >> 4) ^ (l & 3))];
            acc[mt] = MFMA16(af, bf, acc[mt], 0, 0, 0);
        }
    }

    int col = bn*128 + w*16 + (l & 15);
    float wd  = w1[(size_t)1024*1024 + col];
    float b1v = b1[col];
    float w20 = w2[col*2], w21 = w2[col*2 + 1];
    #pragma unroll
    for (int mt = 0; mt < 8; ++mt) {
        float po0[4], po1[4];
        #pragma unroll
        for (int j = 0; j < 4; ++j) {
            int lr = mt*16 + (l >> 4)*4 + j;
            float h = acc[mt][j]
                    + Aq[(size_t)qis[lr]*1024 + col]
                    + Bv[(size_t)ris[lr]*1024 + col]
                    + dsv[lr]*wd + b1v;
            h = fmaxf(h, 0.f);
            po0[j] = h * w20; po1[j] = h * w21;
        }
        #pragma unroll
        for (int s = 1; s < 16; s <<= 1) {
            #pragma unroll
            for (int j = 0; j < 4; ++j) {
                po0[j] += __shfl_xor(po0[j], s, 64);
                po1[j] += __shfl_xor(po1[j], s, 64);
            }
        }
        if ((l & 15) == 0) {
            #pragma unroll
            for (int j = 0; j < 4; ++j) {
                int row = mt*16 + (l >> 4)*4 + j;
                red[(w*128 + row)*2 + 0] = po0[j];
                red[(w*128 + row)*2 + 1] = po1[j];
            }
        }
    }
    __syncthreads();
    if (tid < 256) {
        int row = tid >> 1, cc = tid & 1;
        float s = 0.f;
        #pragma unroll
        for (int ww = 0; ww < 8; ++ww) s += red[(ww*128 + row)*2 + cc];
        partial[((size_t)bn*16384 + bm*128 + row)*2 + cc] = s;
    }
}

__global__ void final_reduce(const float* __restrict__ partial,
                             const float* __restrict__ b2, float* __restrict__ out)
{
    int gidx = blockIdx.x * 256 + threadIdx.x;
    int p = gidx >> 1, c = gidx & 1;
    float s = b2[c];
    #pragma unroll
    for (int nt = 0; nt < 8; ++nt)
        s += partial[((size_t)nt * 16384 + p) * 2 + c];
    out[gidx] = s;
}

extern "C" void kernel_launch(void* const* d_in, const int* in_sizes, int n_in,
                              void* d_out, int out_size, void* d_ws, size_t ws_size,
                              hipStream_t stream) {
    const int*   iq     = (const int*)d_in[0];
    const int*   ir     = (const int*)d_in[1];
    const int*   ql     = (const int*)d_in[2];
    const int*   rl     = (const int*)d_in[3];
    const int*   nqi    = (const int*)d_in[4];
    const int*   nri    = (const int*)d_in[5];
    const float* emb    = (const float*)d_in[6];
    const float* gate_k = (const float*)d_in[7];
    const float* gate_b = (const float*)d_in[8];
    const float* cand_k = (const float*)d_in[9];
    const float* cand_b = (const float*)d_in[10];
    const float* w1     = (const float*)d_in[11];
    const float* b1     = (const float*)d_in[12];
    const float* w2     = (const float*)d_in[13];
    const float* b2     = (const float*)d_in[14];
    float* out = (float*)d_out;
    float* ws  = (float*)d_ws;

    float* Q       = ws;                  // 131072
    float* R       = ws + 131072;         // 131072
    float* A       = ws + 262144;         // 131072
    float* Bv      = ws + 393216;         // 131072
    float* dist    = ws + 524288;         // 16384
    float* partial = ws + 540672;         // 8*16384*2 = 262144
    f16x8* gB      = (f16x8*)(ws + 802816);   // 262144 frags
    f16x8* cB      = (f16x8*)(ws + 1851392);  // 131072 frags
    f16x8* wB      = (f16x8*)(ws + 2375680);  // 131072 frags
    int*   ctr     = (int*)(ws + 2899968);    // 8 ints (claim counters)

    conv_gru<<<1024, 256, 0, stream>>>(gate_k, cand_k, gB, cB, ctr);
    conv_wprod<<<512, 256, 0, stream>>>(w1, wB);
    gru_encode<<<256, 1024, 0, stream>>>(iq, ir, ql, rl, emb, gate_b, cand_b,
                                         gB, cB, ctr, Q, R);
    dist_kernel<<<64, 256, 0, stream>>>(Q, R, dist);
    ab_kernel<<<dim3(4, 8, 2), 256, 0, stream>>>(Q, R, w1, A, Bv);
    pair_gemm<<<dim3(128, 8), 512, 0, stream>>>(Q, R, A, Bv, dist, nqi, nri,
                                                wB, w1, b1, w2, partial);
    final_reduce<<<128, 256, 0, stream>>>(partial, b2, out);
}